// Round 16
// baseline (43.389 us; speedup 1.0000x reference)
//
#include <hip/hip_runtime.h>
#include <hip/hip_bf16.h>

// Chamfer distance via MFMA (bf16 hi/lo split, 3-term Ootomo precision).
// d(x,y) = |y|^2 - 2x.y + |x|^2 packed as a K=13 dot product in
// mfma_f32_32x32x16_bf16 (lanes<32 carry k=0..7 slots, lanes>=32 k=8..15).
// Min over y: in-lane fminf tree over the 16 accumulator regs + shfl_xor(32).
// Math verbatim rounds 4..15 (absmax 0.0 every passing round).
//
// ROUND-16: DIAGNOSTIC. The mfma kernel (~24us) has never been visible in
// top-5 (harness ws-poison fills are ~40us), and 4 rounds of theory-only
// edits (r12-r15) failed to move it. This round runs the main loop TWICE
// (REP=2, unroll 1): min is idempotent (md not re-init between reps), so the
// result is bit-identical and deterministic, but the kernel doubles to ~48us
// and surfaces in top-5 with full PMC. Decision tree on its counters:
//   VALUBusy>55%            -> VALU-bound (accvgpr shuttle) -> cut VALU/MFMA
//   MfmaUtil&VALUBusy<30%   -> per-wave dependency stall -> 2-iter in flight
//   FETCH >> 10MB           -> hidden memory traffic
// r5/6 lesson: no inline asm touching MFMA results.

typedef float f32x16 __attribute__((ext_vector_type(16)));
typedef short bf16x8 __attribute__((ext_vector_type(8)));

constexpr int NPTS    = 8192;
constexpr int BATCH   = 4;
constexpr int NPT_TOT = 2 * BATCH * NPTS;   // 65536 rows total
constexpr int NRED    = 256;
constexpr int REP     = 2;                  // diagnostic repeat (idempotent min)

__device__ __forceinline__ ushort bf16_rne(float v, float& back) {
    unsigned u = __float_as_uint(v);
    unsigned r = (u + 0x7FFFu + ((u >> 16) & 1u)) >> 16;
    back = __uint_as_float(r << 16);
    return (ushort)r;
}

union Frag { ushort u[8]; uint4 q; };

__global__ __launch_bounds__(256)
void chamfer_prep(const float* __restrict__ P1, const float* __restrict__ P2,
                  uint4* __restrict__ Atab, uint4* __restrict__ Btab) {
    const int p = blockIdx.x * 256 + threadIdx.x;          // 0..65535
    const int cloud = p >> 15;
    const float* src = (cloud ? P2 : P1) + (size_t)(p & (BATCH * NPTS - 1)) * 3;
    const float v0 = src[0], v1 = src[1], v2 = src[2];

    float h0f, h1f, h2f, d;
    const ushort h0 = bf16_rne(v0, h0f);
    const ushort h1 = bf16_rne(v1, h1f);
    const ushort h2 = bf16_rne(v2, h2f);
    const ushort l0 = bf16_rne(v0 - h0f, d);
    const ushort l1 = bf16_rne(v1 - h1f, d);
    const ushort l2 = bf16_rne(v2 - h2f, d);
    float n0f, n1f, n2f, m0f, m1f, m2f;
    const ushort n0 = bf16_rne(-2.f * h0f, n0f);
    const ushort n1 = bf16_rne(-2.f * h1f, n1f);
    const ushort n2 = bf16_rne(-2.f * h2f, n2f);
    float l0f, l1f, l2f;
    bf16_rne(v0 - h0f, l0f); bf16_rne(v1 - h1f, l1f); bf16_rne(v2 - h2f, l2f);
    const ushort m0 = bf16_rne(-2.f * l0f, m0f);
    const ushort m1 = bf16_rne(-2.f * l1f, m1f);
    const ushort m2 = bf16_rne(-2.f * l2f, m2f);
    const float s = fmaf(v0, v0, fmaf(v1, v1, v2 * v2));
    float shf;
    const ushort sh = bf16_rne(s, shf);
    const ushort sl = bf16_rne(s - shf, d);
    const ushort ONE = 0x3F80;

    Frag A0; A0.u[0]=h0; A0.u[1]=h1; A0.u[2]=h2; A0.u[3]=l0; A0.u[4]=l1; A0.u[5]=l2; A0.u[6]=h0; A0.u[7]=h1;
    Frag A1; A1.u[0]=h2; A1.u[1]=sh; A1.u[2]=sl; A1.u[3]=ONE; A1.u[4]=ONE; A1.u[5]=0; A1.u[6]=0; A1.u[7]=0;
    Frag B0; B0.u[0]=n0; B0.u[1]=n1; B0.u[2]=n2; B0.u[3]=n0; B0.u[4]=n1; B0.u[5]=n2; B0.u[6]=m0; B0.u[7]=m1;
    Frag B1; B1.u[0]=m2; B1.u[1]=ONE; B1.u[2]=ONE; B1.u[3]=sh; B1.u[4]=sl; B1.u[5]=0; B1.u[6]=0; B1.u[7]=0;

    Atab[p]           = A0.q;
    Atab[NPT_TOT + p] = A1.q;
    Btab[p]           = B0.q;
    Btab[NPT_TOT + p] = B1.q;
}

// 16 MFMA outputs + running min, min3-shaped fminf triples (clang -> v_min3_f32)
#define RED16(D, m) do {                                          \
    float a0 = fminf(fminf((D)[0],  (D)[1]),  (D)[2]);            \
    float a1 = fminf(fminf((D)[3],  (D)[4]),  (D)[5]);            \
    float a2 = fminf(fminf((D)[6],  (D)[7]),  (D)[8]);            \
    float a3 = fminf(fminf((D)[9],  (D)[10]), (D)[11]);           \
    float a4 = fminf(fminf((D)[12], (D)[13]), (D)[14]);           \
    float b0 = fminf(fminf(a0, a1), (D)[15]);                     \
    float b1 = fminf(fminf(a2, a3), a4);                          \
    (m) = fminf(fminf((m), b0), b1);                              \
} while (0)

template<int YSEG>
__global__ __launch_bounds__(256, 4)
void chamfer_mfma(const uint4* __restrict__ Atab, const uint4* __restrict__ Btab,
                  float* __restrict__ mintab) {
    constexpr int SEG = NPTS / YSEG;          // y-points per block
    constexpr int YI  = SEG / 32;
    constexpr int NWG = 16 * 8 * YSEG;
    constexpr int CPX = NWG / 8;              // blocks per XCD chunk

    // XCD-aware bijective swizzle (NWG % 8 == 0): XCD k gets logical ids
    // [k*CPX, (k+1)*CPX) == one comb (comb-major decode below).
    const int l   = blockIdx.x;
    const int swz = (l & 7) * CPX + (l >> 3);
    const int xblk = swz & 15;                // 0..15  (512 x-points per block)
    const int yseg = (swz >> 4) & (YSEG - 1); // 0..YSEG-1
    const int comb = swz >> 4 >> __builtin_ctz(YSEG);   // 0..7  dir*4+b

    const int tid  = threadIdx.x;
    const int lane = tid & 63;
    const int w    = tid >> 6;
    const int col  = lane & 31;
    const int g    = lane >> 5;          // k-half: 0 -> slots 0-7, 1 -> slots 8-15

    const int dir  = comb >> 2;
    const int b    = comb & 3;

    const int xbase = (dir * BATCH + b) * NPTS + xblk * 512 + w * 128;
    const int ybase = ((1 - dir) * BATCH + b) * NPTS + yseg * SEG;

    // ---- stage this block's A-segment (both k-halves) into LDS, once ----
    __shared__ uint4 lds_a[2 * SEG];          // 16 KB @ YSEG=16
    const uint4* As0 = Atab + ybase;
    const uint4* As1 = Atab + NPT_TOT + ybase;
    #pragma unroll
    for (int i = 0; i < SEG / 256; ++i) {
        lds_a[i * 256 + tid]       = As0[i * 256 + tid];
        lds_a[SEG + i * 256 + tid] = As1[i * 256 + tid];
    }

    // 4 B-fragments (128 x-points) in registers — loaded once, L2-resident
    const bf16x8* Bt = (const bf16x8*)Btab;
    bf16x8 Bf[4];
    #pragma unroll
    for (int t = 0; t < 4; ++t)
        Bf[t] = Bt[(size_t)g * NPT_TOT + xbase + t * 32 + col];

    float md[4];
    #pragma unroll
    for (int t = 0; t < 4; ++t) md[t] = 1e30f;

    __syncthreads();

    // ---- main loop, run REP times (idempotent min; bit-identical result) ----
    const f32x16 zero = {};
    const int lbase = g * SEG + col;
    #pragma unroll 1
    for (int rep = 0; rep < REP; ++rep) {
        uint4 Afq = lds_a[lbase];             // prefetch yi=0
        #pragma unroll 2
        for (int yi = 0; yi < YI; ++yi) {
            const uint4 Afc = Afq;
            if (yi + 1 < YI) Afq = lds_a[lbase + (yi + 1) * 32];
            bf16x8 Af;
            __builtin_memcpy(&Af, &Afc, 16);
            f32x16 D;
            D = __builtin_amdgcn_mfma_f32_32x32x16_bf16(Af, Bf[0], zero, 0, 0, 0);
            RED16(D, md[0]);
            D = __builtin_amdgcn_mfma_f32_32x32x16_bf16(Af, Bf[1], zero, 0, 0, 0);
            RED16(D, md[1]);
            D = __builtin_amdgcn_mfma_f32_32x32x16_bf16(Af, Bf[2], zero, 0, 0, 0);
            RED16(D, md[2]);
            D = __builtin_amdgcn_mfma_f32_32x32x16_bf16(Af, Bf[3], zero, 0, 0, 0);
            RED16(D, md[3]);
        }
    }

    // fold half-waves: both k-halves then hold the min over all 32 y-rows
    #pragma unroll
    for (int t = 0; t < 4; ++t)
        md[t] = fminf(md[t], __shfl_xor(md[t], 32, 64));

    if (g == 0) {
        const size_t rowbase = (size_t)yseg * NPT_TOT + xbase;
        #pragma unroll
        for (int t = 0; t < 4; ++t)
            mintab[rowbase + t * 32 + col] = md[t];
    }
}

template<int YSEG>
__global__ __launch_bounds__(256)
void chamfer_reduce(const float* __restrict__ mintab, float* __restrict__ partials) {
    const int r = blockIdx.x * 256 + threadIdx.x;
    float m = mintab[r];
    #pragma unroll
    for (int s = 1; s < YSEG; ++s)
        m = fminf(m, mintab[(size_t)s * NPT_TOT + r]);
    float v = sqrtf(fmaxf(m, 0.f));
    #pragma unroll
    for (int off = 32; off; off >>= 1) v += __shfl_down(v, off, 64);
    __shared__ float ws[4];
    const int tid = threadIdx.x;
    if ((tid & 63) == 0) ws[tid >> 6] = v;
    __syncthreads();
    if (tid == 0)
        partials[blockIdx.x] = ws[0] + ws[1] + ws[2] + ws[3];   // plain store, no init
}

__global__ __launch_bounds__(256)
void chamfer_final(const float* __restrict__ partials, float* __restrict__ out) {
    const int tid = threadIdx.x;
    float v = partials[tid];                 // NRED == 256 == blockDim
    #pragma unroll
    for (int off = 32; off; off >>= 1) v += __shfl_down(v, off, 64);
    __shared__ float ws[4];
    if ((tid & 63) == 0) ws[tid >> 6] = v;
    __syncthreads();
    if (tid == 0)
        out[0] = (ws[0] + ws[1] + ws[2] + ws[3]) * (1.0f / NPT_TOT);
}

extern "C" void kernel_launch(void* const* d_in, const int* in_sizes, int n_in,
                              void* d_out, int out_size, void* d_ws, size_t ws_size,
                              hipStream_t stream) {
    const float* p1 = (const float*)d_in[0];
    const float* p2 = (const float*)d_in[1];
    float* out = (float*)d_out;

    const size_t tab_bytes = (size_t)2 * NPT_TOT * 16;          // 2 MB each
    uint4* Atab   = (uint4*)d_ws;
    uint4* Btab   = (uint4*)((char*)d_ws + tab_bytes);
    float* mintab = (float*)((char*)d_ws + 2 * tab_bytes);

    chamfer_prep<<<dim3(NPT_TOT / 256), 256, 0, stream>>>(p1, p2, Atab, Btab);

    const size_t need16 = 2 * tab_bytes + (size_t)16 * NPT_TOT * 4 + NRED * 4;
    if (ws_size >= need16) {
        constexpr int YSEG = 16;                                 // mintab 4 MB
        float* partials = (float*)((char*)mintab + (size_t)YSEG * NPT_TOT * 4);
        chamfer_mfma<YSEG><<<dim3(16 * 8 * YSEG), 256, 0, stream>>>(Atab, Btab, mintab);
        chamfer_reduce<YSEG><<<dim3(NRED), 256, 0, stream>>>(mintab, partials);
        chamfer_final<<<1, 256, 0, stream>>>(partials, out);
    } else {
        constexpr int YSEG = 8;                                  // mintab 2 MB
        float* partials = (float*)((char*)mintab + (size_t)YSEG * NPT_TOT * 4);
        chamfer_mfma<YSEG><<<dim3(16 * 8 * YSEG), 256, 0, stream>>>(Atab, Btab, mintab);
        chamfer_reduce<YSEG><<<dim3(NRED), 256, 0, stream>>>(mintab, partials);
        chamfer_final<<<1, 256, 0, stream>>>(partials, out);
    }
}

// Round 17
// 29.082 us; speedup vs baseline: 1.4919x; 1.4919x over previous
//
#include <hip/hip_runtime.h>
#include <hip/hip_bf16.h>

// Chamfer distance via MFMA (bf16 hi/lo split, 3-term Ootomo precision).
// d(x,y) = |y|^2 - 2x.y + |x|^2 packed as a K=13 dot product in
// mfma_f32_32x32x16_bf16 (lanes<32 carry k=0..7 slots, lanes>=32 k=8..15).
// Min over y: in-lane fminf tree over the 16 accumulator regs + shfl_xor(32).
// Math verbatim rounds 4..16 (absmax 0.0 every passing round).
//
// Round-17, from r16's REP=2 measurement (loop=13.2us, staging/overhead=12us):
//   (1) YSEG=8: 1024 blocks = ONE block-generation at 4 blocks/CU (staging
//       latency paid once, not twice); LDS 32KB/block (128KB/CU <= 160).
//   (2) Da/Db ping-pong at (256,4): RED16(t) overlaps MFMA(t+1), breaking the
//       per-wave MFMA->min-tree serial chain (loop ran 2x the 6.9us MFMA floor).
//   Register ledger @128 regs: Da+Db 32 + Bf 16 + md 4 + prefetch 8 + zero 16
//   + addr ~12 = ~90 < 128 -> no spill expected. Spill tell: FETCH >> 10MB.
// r5/6 lesson: no inline asm touching MFMA results.

typedef float f32x16 __attribute__((ext_vector_type(16)));
typedef short bf16x8 __attribute__((ext_vector_type(8)));

constexpr int NPTS    = 8192;
constexpr int BATCH   = 4;
constexpr int NPT_TOT = 2 * BATCH * NPTS;   // 65536 rows total
constexpr int NRED    = 256;
constexpr int YSEG    = 8;                  // 1024 y-pts per block segment
constexpr int SEG     = NPTS / YSEG;        // 1024
constexpr int YI      = SEG / 32;           // 32

__device__ __forceinline__ ushort bf16_rne(float v, float& back) {
    unsigned u = __float_as_uint(v);
    unsigned r = (u + 0x7FFFu + ((u >> 16) & 1u)) >> 16;
    back = __uint_as_float(r << 16);
    return (ushort)r;
}

union Frag { ushort u[8]; uint4 q; };

__global__ __launch_bounds__(256)
void chamfer_prep(const float* __restrict__ P1, const float* __restrict__ P2,
                  uint4* __restrict__ Atab, uint4* __restrict__ Btab) {
    const int p = blockIdx.x * 256 + threadIdx.x;          // 0..65535
    const int cloud = p >> 15;
    const float* src = (cloud ? P2 : P1) + (size_t)(p & (BATCH * NPTS - 1)) * 3;
    const float v0 = src[0], v1 = src[1], v2 = src[2];

    float h0f, h1f, h2f, d;
    const ushort h0 = bf16_rne(v0, h0f);
    const ushort h1 = bf16_rne(v1, h1f);
    const ushort h2 = bf16_rne(v2, h2f);
    const ushort l0 = bf16_rne(v0 - h0f, d);
    const ushort l1 = bf16_rne(v1 - h1f, d);
    const ushort l2 = bf16_rne(v2 - h2f, d);
    float n0f, n1f, n2f, m0f, m1f, m2f;
    const ushort n0 = bf16_rne(-2.f * h0f, n0f);
    const ushort n1 = bf16_rne(-2.f * h1f, n1f);
    const ushort n2 = bf16_rne(-2.f * h2f, n2f);
    float l0f, l1f, l2f;
    bf16_rne(v0 - h0f, l0f); bf16_rne(v1 - h1f, l1f); bf16_rne(v2 - h2f, l2f);
    const ushort m0 = bf16_rne(-2.f * l0f, m0f);
    const ushort m1 = bf16_rne(-2.f * l1f, m1f);
    const ushort m2 = bf16_rne(-2.f * l2f, m2f);
    const float s = fmaf(v0, v0, fmaf(v1, v1, v2 * v2));
    float shf;
    const ushort sh = bf16_rne(s, shf);
    const ushort sl = bf16_rne(s - shf, d);
    const ushort ONE = 0x3F80;

    Frag A0; A0.u[0]=h0; A0.u[1]=h1; A0.u[2]=h2; A0.u[3]=l0; A0.u[4]=l1; A0.u[5]=l2; A0.u[6]=h0; A0.u[7]=h1;
    Frag A1; A1.u[0]=h2; A1.u[1]=sh; A1.u[2]=sl; A1.u[3]=ONE; A1.u[4]=ONE; A1.u[5]=0; A1.u[6]=0; A1.u[7]=0;
    Frag B0; B0.u[0]=n0; B0.u[1]=n1; B0.u[2]=n2; B0.u[3]=n0; B0.u[4]=n1; B0.u[5]=n2; B0.u[6]=m0; B0.u[7]=m1;
    Frag B1; B1.u[0]=m2; B1.u[1]=ONE; B1.u[2]=ONE; B1.u[3]=sh; B1.u[4]=sl; B1.u[5]=0; B1.u[6]=0; B1.u[7]=0;

    Atab[p]           = A0.q;
    Atab[NPT_TOT + p] = A1.q;
    Btab[p]           = B0.q;
    Btab[NPT_TOT + p] = B1.q;
}

// 16 MFMA outputs + running min, min3-shaped fminf triples (clang -> v_min3_f32)
#define RED16(D, m) do {                                          \
    float a0 = fminf(fminf((D)[0],  (D)[1]),  (D)[2]);            \
    float a1 = fminf(fminf((D)[3],  (D)[4]),  (D)[5]);            \
    float a2 = fminf(fminf((D)[6],  (D)[7]),  (D)[8]);            \
    float a3 = fminf(fminf((D)[9],  (D)[10]), (D)[11]);           \
    float a4 = fminf(fminf((D)[12], (D)[13]), (D)[14]);           \
    float b0 = fminf(fminf(a0, a1), (D)[15]);                     \
    float b1 = fminf(fminf(a2, a3), a4);                          \
    (m) = fminf(fminf((m), b0), b1);                              \
} while (0)

__global__ __launch_bounds__(256, 4)
void chamfer_mfma(const uint4* __restrict__ Atab, const uint4* __restrict__ Btab,
                  float* __restrict__ mintab) {
    constexpr int NWG = 16 * 8 * YSEG;        // 1024 blocks: ONE generation
    constexpr int CPX = NWG / 8;              // 128 blocks per XCD chunk

    // XCD-aware bijective swizzle: XCD k gets swz in [k*CPX,(k+1)*CPX) == comb k.
    const int l   = blockIdx.x;
    const int swz = (l & 7) * CPX + (l >> 3);
    const int xblk = swz & 15;                // 0..15  (512 x-points per block)
    const int yseg = (swz >> 4) & (YSEG - 1); // 0..7
    const int comb = swz >> 7;                // 0..7  dir*4+b

    const int tid  = threadIdx.x;
    const int lane = tid & 63;
    const int w    = tid >> 6;
    const int col  = lane & 31;
    const int g    = lane >> 5;          // k-half: 0 -> slots 0-7, 1 -> slots 8-15

    const int dir  = comb >> 2;
    const int b    = comb & 3;

    const int xbase = (dir * BATCH + b) * NPTS + xblk * 512 + w * 128;
    const int ybase = ((1 - dir) * BATCH + b) * NPTS + yseg * SEG;

    // ---- stage this block's A-segment (both k-halves) into LDS, once ----
    __shared__ uint4 lds_a[2 * SEG];          // 32 KB
    const uint4* As0 = Atab + ybase;
    const uint4* As1 = Atab + NPT_TOT + ybase;
    #pragma unroll
    for (int i = 0; i < SEG / 256; ++i) {
        lds_a[i * 256 + tid]       = As0[i * 256 + tid];
        lds_a[SEG + i * 256 + tid] = As1[i * 256 + tid];
    }

    // 4 B-fragments (128 x-points) in registers — loaded once, L2-resident
    const bf16x8* Bt = (const bf16x8*)Btab;
    bf16x8 Bf[4];
    #pragma unroll
    for (int t = 0; t < 4; ++t)
        Bf[t] = Bt[(size_t)g * NPT_TOT + xbase + t * 32 + col];

    float md[4];
    #pragma unroll
    for (int t = 0; t < 4; ++t) md[t] = 1e30f;

    __syncthreads();

    // ---- main loop: prefetch + Da/Db ping-pong (RED16(t) overlaps MFMA(t+1)) ----
    const f32x16 zero = {};
    const int lbase = g * SEG + col;
    uint4 Afq = lds_a[lbase];                 // prefetch yi=0
    #pragma unroll 2
    for (int yi = 0; yi < YI; ++yi) {
        const uint4 Afc = Afq;
        if (yi + 1 < YI) Afq = lds_a[lbase + (yi + 1) * 32];
        bf16x8 Af;
        __builtin_memcpy(&Af, &Afc, 16);
        f32x16 Da = __builtin_amdgcn_mfma_f32_32x32x16_bf16(Af, Bf[0], zero, 0, 0, 0);
        f32x16 Db = __builtin_amdgcn_mfma_f32_32x32x16_bf16(Af, Bf[1], zero, 0, 0, 0);
        RED16(Da, md[0]);
        Da = __builtin_amdgcn_mfma_f32_32x32x16_bf16(Af, Bf[2], zero, 0, 0, 0);
        RED16(Db, md[1]);
        Db = __builtin_amdgcn_mfma_f32_32x32x16_bf16(Af, Bf[3], zero, 0, 0, 0);
        RED16(Da, md[2]);
        RED16(Db, md[3]);
    }

    // fold half-waves: both k-halves then hold the min over all 32 y-rows
    #pragma unroll
    for (int t = 0; t < 4; ++t)
        md[t] = fminf(md[t], __shfl_xor(md[t], 32, 64));

    if (g == 0) {
        const size_t rowbase = (size_t)yseg * NPT_TOT + xbase;
        #pragma unroll
        for (int t = 0; t < 4; ++t)
            mintab[rowbase + t * 32 + col] = md[t];
    }
}

__global__ __launch_bounds__(256)
void chamfer_reduce(const float* __restrict__ mintab, float* __restrict__ partials) {
    const int r = blockIdx.x * 256 + threadIdx.x;
    float m = mintab[r];
    #pragma unroll
    for (int s = 1; s < YSEG; ++s)
        m = fminf(m, mintab[(size_t)s * NPT_TOT + r]);
    float v = sqrtf(fmaxf(m, 0.f));
    #pragma unroll
    for (int off = 32; off; off >>= 1) v += __shfl_down(v, off, 64);
    __shared__ float ws[4];
    const int tid = threadIdx.x;
    if ((tid & 63) == 0) ws[tid >> 6] = v;
    __syncthreads();
    if (tid == 0)
        partials[blockIdx.x] = ws[0] + ws[1] + ws[2] + ws[3];   // plain store, no init
}

__global__ __launch_bounds__(256)
void chamfer_final(const float* __restrict__ partials, float* __restrict__ out) {
    const int tid = threadIdx.x;
    float v = partials[tid];                 // NRED == 256 == blockDim
    #pragma unroll
    for (int off = 32; off; off >>= 1) v += __shfl_down(v, off, 64);
    __shared__ float ws[4];
    if ((tid & 63) == 0) ws[tid >> 6] = v;
    __syncthreads();
    if (tid == 0)
        out[0] = (ws[0] + ws[1] + ws[2] + ws[3]) * (1.0f / NPT_TOT);
}

extern "C" void kernel_launch(void* const* d_in, const int* in_sizes, int n_in,
                              void* d_out, int out_size, void* d_ws, size_t ws_size,
                              hipStream_t stream) {
    const float* p1 = (const float*)d_in[0];
    const float* p2 = (const float*)d_in[1];
    float* out = (float*)d_out;

    const size_t tab_bytes = (size_t)2 * NPT_TOT * 16;          // 2 MB each
    uint4* Atab   = (uint4*)d_ws;
    uint4* Btab   = (uint4*)((char*)d_ws + tab_bytes);
    float* mintab = (float*)((char*)d_ws + 2 * tab_bytes);      // 2 MB @ YSEG=8
    float* partials = (float*)((char*)mintab + (size_t)YSEG * NPT_TOT * 4);

    chamfer_prep<<<dim3(NPT_TOT / 256), 256, 0, stream>>>(p1, p2, Atab, Btab);
    chamfer_mfma<<<dim3(16 * 8 * YSEG), 256, 0, stream>>>(Atab, Btab, mintab);
    chamfer_reduce<<<dim3(NRED), 256, 0, stream>>>(mintab, partials);
    chamfer_final<<<1, 256, 0, stream>>>(partials, out);
}